// Round 5
// baseline (544.151 us; speedup 1.0000x reference)
//
#include <hip/hip_runtime.h>
#include <math.h>

#define S_LEN   8192
#define DMODEL  1024
#define B_SZ    2
#define NH      16
#define HD      64
#define KSEL    1024
#define WINDOW  512
#define NEG_BIG -1000000000.0f
#define RMSEPS  1.1920929e-07f

typedef short bf16x8 __attribute__((ext_vector_type(8)));
typedef float f32x4 __attribute__((ext_vector_type(4)));

// ---------------------------------------------------------------- zero output
__global__ void k_zero(float4* __restrict__ o, int n4) {
    int i = blockIdx.x * blockDim.x + threadIdx.x;
    if (i < n4) o[i] = make_float4(0.f, 0.f, 0.f, 0.f);
}

// ---------------------------------------------------------- routing scores
__global__ __launch_bounds__(256) void k_scores(const float* __restrict__ x,
                                                const float* __restrict__ cheby,
                                                float* __restrict__ scores) {
    int lin = blockIdx.x;
    int b = lin / (S_LEN - 1);
    int t = lin % (S_LEN - 1);
    const float4* xr = (const float4*)(x + ((size_t)b * S_LEN + t + 1) * DMODEL);
    const float4* cr = (const float4*)(cheby + ((size_t)b * S_LEN + t) * DMODEL);
    float4 xv = xr[threadIdx.x];
    float4 cv = cr[threadIdx.x];
    double acc = 0.0;
    {
        float vs[4] = {xv.x, xv.y, xv.z, xv.w};
        float cs[4] = {cv.x, cv.y, cv.z, cv.w};
#pragma unroll
        for (int j = 0; j < 4; ++j) {
            float ax = fmaxf(fabsf(vs[j]), 1e-7f);
            float ss = copysignf(1.0f - 1.0f / (1.0f + ax), vs[j]);
            acc += (double)fabsf(ss - cs[j]);
        }
    }
    int lane = threadIdx.x & 63, wid = threadIdx.x >> 6;
#pragma unroll
    for (int o = 32; o; o >>= 1) acc += __shfl_down(acc, o);
    __shared__ double wred[4];
    if (lane == 0) wred[wid] = acc;
    __syncthreads();
    if (threadIdx.x == 0) {
        double tot = wred[0] + wred[1] + wred[2] + wred[3];
        scores[(size_t)b * S_LEN + t] = (float)(tot * (1.0 / 1024.0));
    }
}

// ------------------------------------------------------------------- top-K
__global__ __launch_bounds__(1024) void k_topk(const float* __restrict__ scores,
                                               int* __restrict__ indices) {
    const int b = blockIdx.x;
    const int tid = threadIdx.x;
    const int lane = tid & 63, wid = tid >> 6;
    __shared__ unsigned vals[S_LEN];
    __shared__ unsigned hist[16][256];
    __shared__ unsigned sfx[256];
    __shared__ unsigned wsum[16];
    __shared__ unsigned bcast[2];
    __shared__ float fred[16];

    float mx = -1e30f;
    for (int i = tid; i < S_LEN - 1; i += 1024) {
        float v = scores[(size_t)b * S_LEN + i];
        vals[i] = __float_as_uint(v);
        mx = fmaxf(mx, v);
    }
#pragma unroll
    for (int o = 32; o; o >>= 1) mx = fmaxf(mx, __shfl_down(mx, o));
    if (lane == 0) fred[wid] = mx;
    __syncthreads();
    if (tid == 0) {
        float m2 = fred[0];
        for (int w = 1; w < 16; ++w) m2 = fmaxf(m2, fred[w]);
        vals[S_LEN - 1] = __float_as_uint(m2);
    }
    __syncthreads();

    unsigned prefix = 0, remaining = KSEL;
    for (int p = 3; p >= 0; --p) {
        unsigned hm = (p == 3) ? 0u : (0xFFFFFFFFu << ((p + 1) * 8));
        for (int i = tid; i < 4096; i += 1024) ((unsigned*)hist)[i] = 0u;
        __syncthreads();
        for (int i = tid; i < S_LEN; i += 1024) {
            unsigned v = vals[i];
            if ((v & hm) == (prefix & hm))
                atomicAdd(&hist[wid][(v >> (p * 8)) & 255u], 1u);
        }
        __syncthreads();
        if (tid < 256) {
            unsigned h = 0;
#pragma unroll
            for (int w = 0; w < 16; ++w) h += hist[w][tid];
            sfx[tid] = h;
        }
        __syncthreads();
        for (int off = 1; off < 256; off <<= 1) {
            unsigned add = 0;
            if (tid < 256 && tid + off < 256) add = sfx[tid + off];
            __syncthreads();
            if (tid < 256) sfx[tid] += add;
            __syncthreads();
        }
        if (tid < 256) {
            unsigned Sb  = sfx[tid];
            unsigned Sb1 = (tid < 255) ? sfx[tid + 1] : 0u;
            if (Sb >= remaining && Sb1 < remaining) { bcast[0] = (unsigned)tid; bcast[1] = Sb1; }
        }
        __syncthreads();
        prefix |= bcast[0] << (p * 8);
        remaining -= bcast[1];
        __syncthreads();
    }
    const unsigned T = prefix;
    const unsigned need = remaining;

    const int p0 = tid * 8;
    unsigned vloc[8];
#pragma unroll
    for (int j = 0; j < 8; ++j) vloc[j] = vals[p0 + j];

    unsigned eqpre[8]; unsigned myeq = 0;
#pragma unroll
    for (int j = 0; j < 8; ++j) { eqpre[j] = myeq; myeq += (vloc[j] == T) ? 1u : 0u; }
    unsigned inc = myeq;
#pragma unroll
    for (int o = 1; o < 64; o <<= 1) { unsigned u = __shfl_up(inc, o); if (lane >= o) inc += u; }
    if (lane == 63) wsum[wid] = inc;
    __syncthreads();
    if (wid == 0) {
        unsigned w = (lane < 16) ? wsum[lane] : 0u;
        unsigned winc = w;
#pragma unroll
        for (int o = 1; o < 16; o <<= 1) { unsigned u = __shfl_up(winc, o); if (lane >= o) winc += u; }
        if (lane < 16) wsum[lane] = winc - w;
    }
    __syncthreads();
    const unsigned eqbase = wsum[wid] + inc - myeq;
    __syncthreads();

    unsigned fpre[8]; unsigned myf = 0; unsigned fl = 0;
#pragma unroll
    for (int j = 0; j < 8; ++j) {
        bool f = (vloc[j] > T) || ((vloc[j] == T) && (eqbase + eqpre[j] < need));
        fl |= (f ? 1u : 0u) << j;
        fpre[j] = myf;
        myf += f ? 1u : 0u;
    }
    unsigned inc2 = myf;
#pragma unroll
    for (int o = 1; o < 64; o <<= 1) { unsigned u = __shfl_up(inc2, o); if (lane >= o) inc2 += u; }
    if (lane == 63) wsum[wid] = inc2;
    __syncthreads();
    if (wid == 0) {
        unsigned w = (lane < 16) ? wsum[lane] : 0u;
        unsigned winc = w;
#pragma unroll
        for (int o = 1; o < 16; o <<= 1) { unsigned u = __shfl_up(winc, o); if (lane >= o) winc += u; }
        if (lane < 16) wsum[lane] = winc - w;
    }
    __syncthreads();
    const unsigned fbase = wsum[wid] + inc2 - myf;
#pragma unroll
    for (int j = 0; j < 8; ++j)
        if ((fl >> j) & 1u)
            indices[b * KSEL + fbase + fpre[j]] = p0 + j;
}

// ------------------------------------------------------------- RoPE tables
__global__ void k_rope_tab(const int* __restrict__ idxs,
                           float* __restrict__ rcos, float* __restrict__ rsin) {
    int g = blockIdx.x * blockDim.x + threadIdx.x;
    if (g >= B_SZ * KSEL * 32) return;
    int i = g & 31, bm = g >> 5;
    int b = bm >> 10, m = bm & 1023;
    float pos = (float)idxs[b * KSEL + m];
    double th = exp2(-(double)i * (13.287712379549449 / 32.0));
    float freq = pos * (float)th;
    float s, c;
    sincosf(freq, &s, &c);
    rcos[g] = c;
    rsin[g] = s;
}

__global__ __launch_bounds__(256) void k_rope_apply(float* __restrict__ qkv,
                                                    const float* __restrict__ rcos,
                                                    const float* __restrict__ rsin) {
    int bm = blockIdx.x;
    float* row = qkv + (size_t)bm * 4096;
    for (int p = threadIdx.x; p < 1536; p += 256) {
        int s = p / 512, r = p % 512;
        int h = r >> 5, i = r & 31;
        float c = rcos[bm * 32 + i], sn = rsin[bm * 32 + i];
        int off = s * 1024 + h * 64 + 2 * i;
        float x1 = row[off], x2 = row[off + 1];
        row[off]     = x1 * c - x2 * sn;
        row[off + 1] = x1 * sn + x2 * c;
    }
}

// -------------------------------------------- bf16 split helpers (hi/lo x3)
__device__ __forceinline__ unsigned pack_hi2(float a, float b) {
    return (__float_as_uint(a) >> 16) | (__float_as_uint(b) & 0xFFFF0000u);
}
__device__ __forceinline__ unsigned pack_lo2(float a, float b) {
    unsigned ua = __float_as_uint(a), ub = __float_as_uint(b);
    float ra = a - __uint_as_float(ua & 0xFFFF0000u);
    float rb = b - __uint_as_float(ub & 0xFFFF0000u);
    unsigned la = __float_as_uint(ra), lb = __float_as_uint(rb);
    la = la + 0x7FFFu + ((la >> 16) & 1u);
    lb = lb + 0x7FFFu + ((lb >> 16) & 1u);
    return (la >> 16) | (lb & 0xFFFF0000u);
}
__device__ __forceinline__ uint4 pack_hi8(float4 a, float4 b) {
    return make_uint4(pack_hi2(a.x, a.y), pack_hi2(a.z, a.w),
                      pack_hi2(b.x, b.y), pack_hi2(b.z, b.w));
}
__device__ __forceinline__ uint4 pack_lo8(float4 a, float4 b) {
    return make_uint4(pack_lo2(a.x, a.y), pack_lo2(a.z, a.w),
                      pack_lo2(b.x, b.y), pack_lo2(b.z, b.w));
}

// Packed bf16 hi/lo layout: row-major [row][kblk][64] ushorts,
// where within a 64-ushort (128B) group: [0,32) = hi of k in [kblk*32,kblk*32+32),
// [32,64) = lo. 16B chunk c of a group is stored at slot (c ^ (row&7)) in LDS.

// ------------------------ split a [R][1024] fp32 matrix into packed hi/lo
__global__ __launch_bounds__(256) void k_splitW(const float* __restrict__ src,
                                                ushort* __restrict__ dst, int total) {
    int idx = blockIdx.x * 256 + threadIdx.x;
    int base = idx * 8;
    if (base >= total) return;
    int row = base >> 10, k = base & 1023;
    int kblk = k >> 5, ko = k & 31;
    float4 f0 = *(const float4*)(src + base);
    float4 f1 = *(const float4*)(src + base + 4);
    ushort* d = dst + ((size_t)row * 32 + kblk) * 64 + ko;
    *(uint4*)d        = pack_hi8(f0, f1);
    *(uint4*)(d + 32) = pack_lo8(f0, f1);
}

// -------------------- gather selected x rows + split into packed hi/lo
__global__ __launch_bounds__(256) void k_splitX(const float* __restrict__ x,
                                                const int* __restrict__ idxs,
                                                ushort* __restrict__ dst) {
    const int r = blockIdx.x;
    const int b = r >> 10, m = r & 1023;
    const float* src = x + ((size_t)b * S_LEN + idxs[b * KSEL + m]) * DMODEL;
    const int t = threadIdx.x;
    const int k = t * 4;
    float4 f = *(const float4*)(src + k);
    int kblk = k >> 5, ko = k & 31;
    ushort* d = dst + ((size_t)r * 32 + kblk) * 64 + ko;
    uint2 hi = make_uint2(pack_hi2(f.x, f.y), pack_hi2(f.z, f.w));
    uint2 lo = make_uint2(pack_lo2(f.x, f.y), pack_lo2(f.z, f.w));
    *(uint2*)d        = hi;
    *(uint2*)(d + 32) = lo;
}

// -------------------------------- QKV GEMM: packed bf16 hi/lo, MFMA x3
// C[r,n] = sum_k X[r,k] * Wq[n,k]; 128x128 tile, BK=32, 4 waves (2x2 of 64x64).
__global__ __launch_bounds__(256) void k_qkv(const ushort* __restrict__ Xp,
                                             const ushort* __restrict__ Wp,
                                             float* __restrict__ qkv) {
    __shared__ ushort As[128][64];
    __shared__ ushort Bs[128][64];
    const int tid = threadIdx.x;
    const int bm = blockIdx.x, bn = blockIdx.y;
    const int srow = tid >> 1, half = tid & 1;
    const int r7 = srow & 7, c0 = half * 4;
    const ushort* asrc = Xp + ((size_t)(bm * 128 + srow) * 32) * 64 + half * 32;
    const ushort* bsrc = Wp + ((size_t)(bn * 128 + srow) * 32) * 64 + half * 32;
    const int wave = tid >> 6, lane = tid & 63;
    const int wm = wave >> 1, wn = wave & 1;
    const int fr = lane & 15, g = lane >> 4;
    f32x4 acc[4][4];
#pragma unroll
    for (int i = 0; i < 4; ++i)
#pragma unroll
        for (int j = 0; j < 4; ++j) acc[i][j] = (f32x4){0.f, 0.f, 0.f, 0.f};
    uint4 av[4], bv[4];
#pragma unroll
    for (int i = 0; i < 4; ++i) {
        av[i] = ((const uint4*)asrc)[i];
        bv[i] = ((const uint4*)bsrc)[i];
    }
    for (int kb = 0; kb < 32; ++kb) {
        __syncthreads();
#pragma unroll
        for (int j = 0; j < 4; ++j) {
            *(uint4*)&As[srow][((c0 + j) ^ r7) * 8] = av[j];
            *(uint4*)&Bs[srow][((c0 + j) ^ r7) * 8] = bv[j];
        }
        __syncthreads();
        if (kb + 1 < 32) {
#pragma unroll
            for (int i = 0; i < 4; ++i) {
                av[i] = ((const uint4*)(asrc + (kb + 1) * 64))[i];
                bv[i] = ((const uint4*)(bsrc + (kb + 1) * 64))[i];
            }
        }
        bf16x8 ah[4], al[4], bh[4], bl[4];
#pragma unroll
        for (int i = 0; i < 4; ++i) {
            int ra = wm * 64 + i * 16 + fr;
            int rb = wn * 64 + i * 16 + fr;
            ah[i] = *(const bf16x8*)&As[ra][((g)     ^ (ra & 7)) * 8];
            al[i] = *(const bf16x8*)&As[ra][((4 + g) ^ (ra & 7)) * 8];
            bh[i] = *(const bf16x8*)&Bs[rb][((g)     ^ (rb & 7)) * 8];
            bl[i] = *(const bf16x8*)&Bs[rb][((4 + g) ^ (rb & 7)) * 8];
        }
#pragma unroll
        for (int mi = 0; mi < 4; ++mi)
#pragma unroll
            for (int ni = 0; ni < 4; ++ni) {
                acc[mi][ni] = __builtin_amdgcn_mfma_f32_16x16x32_bf16(ah[mi], bh[ni], acc[mi][ni], 0, 0, 0);
                acc[mi][ni] = __builtin_amdgcn_mfma_f32_16x16x32_bf16(ah[mi], bl[ni], acc[mi][ni], 0, 0, 0);
                acc[mi][ni] = __builtin_amdgcn_mfma_f32_16x16x32_bf16(al[mi], bh[ni], acc[mi][ni], 0, 0, 0);
            }
    }
    const int r0 = g * 4;
#pragma unroll
    for (int mi = 0; mi < 4; ++mi)
#pragma unroll
        for (int ni = 0; ni < 4; ++ni) {
#pragma unroll
            for (int r = 0; r < 4; ++r) {
                int row = bm * 128 + wm * 64 + mi * 16 + r0 + r;
                int col = bn * 128 + wn * 64 + ni * 16 + fr;
                qkv[(size_t)row * 4096 + col] = acc[mi][ni][r];
            }
        }
}

// ------------------------------------------------------------- attention
// grid: 512 = b(2) x h(16) x qblock(16 of 64 queries); 256 threads = 4 waves.
// Wave = 16 queries x 4 dim-quarters, both streams. Epilogue writes the
// packed bf16 hi/lo of (o1 - lam*o2) directly (feeds k_ogemm).
__global__ __launch_bounds__(256) void k_attn(const float* __restrict__ qkv,
                                              const int* __restrict__ idxs,
                                              const float* __restrict__ dll,
                                              ushort* __restrict__ Ap) {
    const int lin = blockIdx.x;
    const int qb = lin & 15;
    const int h  = (lin >> 4) & 15;
    const int b  = lin >> 8;
    const int tid = threadIdx.x;
    const int wave = tid >> 6, lane = tid & 63;
    const int qloc = lane >> 2, dp = lane & 3;
    const int qg = qb * 64 + wave * 16 + qloc;
    const int c = qg >> 8;
    const int cstart = (c >= 1) ? (c - 1) * 256 : 0;

    __shared__ float Kt[64][68];
    __shared__ float Vt[64][68];
    __shared__ int wred[4];

    const int* pidx = idxs + b * KSEL;
    const int pq = pidx[qg];
    int blo_ = cstart, bhi_ = qg;
    const int target = pq - WINDOW;
    while (blo_ < bhi_) {
        int mid = (blo_ + bhi_) >> 1;
        if (pidx[mid] > target) bhi_ = mid; else blo_ = mid + 1;
    }
    const int jlo = blo_;

    int wlo = jlo;
#pragma unroll
    for (int o = 32; o; o >>= 1) wlo = min(wlo, __shfl_xor(wlo, o));
    if (lane == 0) wred[wave] = wlo;
    __syncthreads();
    const int blo = min(min(wred[0], wred[1]), min(wred[2], wred[3]));
    const int t0 = blo >> 6;
    const int t1 = qb;

    const float* qrow = qkv + (size_t)(b * KSEL + qg) * 4096 + h * 64 + dp * 16;
    float4 q1v[4], q2v[4];
#pragma unroll
    for (int i = 0; i < 4; ++i) {
        q1v[i] = ((const float4*)qrow)[i];
        q2v[i] = ((const float4*)(qrow + 1024))[i];
    }
    float4 a1[4], a2[4];
#pragma unroll
    for (int i = 0; i < 4; ++i) {
        a1[i] = make_float4(0.f, 0.f, 0.f, 0.f);
        a2[i] = make_float4(0.f, 0.f, 0.f, 0.f);
    }
    float m1 = NEG_BIG, l1 = 0.f, m2 = NEG_BIG, l2 = 0.f;

    const float* kvsrc = qkv + (size_t)b * KSEL * 4096 + 2048 + h * 64;

    for (int t = t0; t <= t1; ++t) {
        __syncthreads();
        {
            const int kk = tid >> 2, cc = (tid & 3) * 16;
            const float* src = kvsrc + (size_t)(t * 64 + kk) * 4096 + cc;
#pragma unroll
            for (int i = 0; i < 4; ++i) {
                *(float4*)&Kt[kk][cc + 4 * i] = *(const float4*)(src + 4 * i);
                *(float4*)&Vt[kk][cc + 4 * i] = *(const float4*)(src + 1024 + 4 * i);
            }
        }
        __syncthreads();
        if (t * 64 + 63 >= wlo) {
#pragma unroll 4
            for (int j = 0; j < 64; ++j) {
                const int jg = t * 64 + j;
                const float* kr = &Kt[j][dp * 16];
                float4 k0 = *(const float4*)&kr[0];
                float4 k1 = *(const float4*)&kr[4];
                float4 k2 = *(const float4*)&kr[8];
                float4 k3 = *(const float4*)&kr[12];
                float p1a = q1v[0].x*k0.x + q1v[0].y*k0.y + q1v[0].z*k0.z + q1v[0].w*k0.w
                          + q1v[1].x*k1.x + q1v[1].y*k1.y + q1v[1].z*k1.z + q1v[1].w*k1.w
                          + q1v[2].x*k2.x + q1v[2].y*k2.y + q1v[2].z*k2.z + q1v[2].w*k2.w
                          + q1v[3].x*k3.x + q1v[3].y*k3.y + q1v[3].z*k3.z + q1v[3].w*k3.w;
                float p2a = q2v[0].x*k0.x + q2v[0].y*k0.y + q2v[0].z*k0.z + q2v[0].w*k0.w
                          + q2v[1].x*k1.x + q2v[1].y*k1.y + q2v[1].z*k1.z + q2v[1].w*k1.w
                          + q2v[2].x*k2.x + q2v[2].y*k2.y + q2v[2].z*k2.z + q2v[2].w*k2.w
                          + q2v[3].x*k3.x + q2v[3].y*k3.y + q2v[3].z*k3.z + q2v[3].w*k3.w;
                p1a += __shfl_xor(p1a, 1); p1a += __shfl_xor(p1a, 2);
                p2a += __shfl_xor(p2a, 1); p2a += __shfl_xor(p2a, 2);
                const bool ok = (jg >= jlo) && (jg <= qg);
                float sc1 = ok ? p1a * 0.125f : NEG_BIG;
                float sc2 = ok ? p2a * 0.125f : NEG_BIG;
                float d1 = sc1 - m1, d2 = sc2 - m2;
                if (__any(fmaxf(d1, d2) > 8.0f)) {
                    float nm1 = fmaxf(m1, sc1), nm2 = fmaxf(m2, sc2);
                    float sf1 = __expf(m1 - nm1), sf2 = __expf(m2 - nm2);
                    l1 *= sf1; l2 *= sf2;
#pragma unroll
                    for (int i = 0; i < 4; ++i) {
                        a1[i].x *= sf1; a1[i].y *= sf1; a1[i].z *= sf1; a1[i].w *= sf1;
                        a2[i].x *= sf2; a2[i].y *= sf2; a2[i].z *= sf2; a2[i].w *= sf2;
                    }
                    m1 = nm1; m2 = nm2;
                    d1 = sc1 - m1; d2 = sc2 - m2;
                }
                float p1 = __expf(d1), p2 = __expf(d2);
                l1 += p1; l2 += p2;
                const float* vr = &Vt[j][dp * 16];
                float4 v0 = *(const float4*)&vr[0];
                float4 v1 = *(const float4*)&vr[4];
                float4 v2 = *(const float4*)&vr[8];
                float4 v3 = *(const float4*)&vr[12];
                a1[0].x += p1*v0.x; a1[0].y += p1*v0.y; a1[0].z += p1*v0.z; a1[0].w += p1*v0.w;
                a1[1].x += p1*v1.x; a1[1].y += p1*v1.y; a1[1].z += p1*v1.z; a1[1].w += p1*v1.w;
                a1[2].x += p1*v2.x; a1[2].y += p1*v2.y; a1[2].z += p1*v2.z; a1[2].w += p1*v2.w;
                a1[3].x += p1*v3.x; a1[3].y += p1*v3.y; a1[3].z += p1*v3.z; a1[3].w += p1*v3.w;
                a2[0].x += p2*v0.x; a2[0].y += p2*v0.y; a2[0].z += p2*v0.z; a2[0].w += p2*v0.w;
                a2[1].x += p2*v1.x; a2[1].y += p2*v1.y; a2[1].z += p2*v1.z; a2[1].w += p2*v1.w;
                a2[2].x += p2*v2.x; a2[2].y += p2*v2.y; a2[2].z += p2*v2.z; a2[2].w += p2*v2.w;
                a2[3].x += p2*v3.x; a2[3].y += p2*v3.y; a2[3].z += p2*v3.z; a2[3].w += p2*v3.w;
            }
        }
    }
    const float i1 = 1.0f / l1, i2 = 1.0f / l2;
    const float lam = 1.0f / (1.0f + __expf(-dll[h]));
    float df[16];
#pragma unroll
    for (int i = 0; i < 4; ++i) {
        df[i*4+0] = a1[i].x * i1 - lam * (a2[i].x * i2);
        df[i*4+1] = a1[i].y * i1 - lam * (a2[i].y * i2);
        df[i*4+2] = a1[i].z * i1 - lam * (a2[i].z * i2);
        df[i*4+3] = a1[i].w * i1 - lam * (a2[i].w * i2);
    }
    const int r = b * KSEL + qg;
    const int kblk = h * 2 + (dp >> 1);
    const int ko = (dp & 1) * 16;
    ushort* d = Ap + ((size_t)r * 32 + kblk) * 64 + ko;
    float4 f0 = make_float4(df[0], df[1], df[2], df[3]);
    float4 f1 = make_float4(df[4], df[5], df[6], df[7]);
    float4 f2 = make_float4(df[8], df[9], df[10], df[11]);
    float4 f3 = make_float4(df[12], df[13], df[14], df[15]);
    *(uint4*)(d)      = pack_hi8(f0, f1);
    *(uint4*)(d + 8)  = pack_hi8(f2, f3);
    *(uint4*)(d + 32) = pack_lo8(f0, f1);
    *(uint4*)(d + 40) = pack_lo8(f2, f3);
}

// ---------------------- output GEMM: y = diff @ Wo^T (diff pre-packed by attn)
// M=2048, N=1024, K=1024. 128x64 tile, BK=32, 4 waves (2x2 of 64x32).
__global__ __launch_bounds__(256) void k_ogemm(const ushort* __restrict__ Ap,
                                               const ushort* __restrict__ Wp,
                                               float* __restrict__ y) {
    __shared__ ushort As[128][64];
    __shared__ ushort Bs[64][64];
    const int tid = threadIdx.x;
    const int bm = blockIdx.x, bn = blockIdx.y;
    const int srow = tid >> 1, half = tid & 1;
    const int ra7 = srow & 7, ca0 = half * 4;
    const ushort* asrc = Ap + ((size_t)(bm * 128 + srow) * 32) * 64 + half * 32;
    const int brow = tid >> 2, q = tid & 3;
    const int rb7 = brow & 7;
    const ushort* bsrc = Wp + ((size_t)(bn * 64 + brow) * 32) * 64 + q * 16;
    const int wave = tid >> 6, lane = tid & 63;
    const int wm = wave >> 1, wn = wave & 1;
    const int fr = lane & 15, g = lane >> 4;
    f32x4 acc[4][2];
#pragma unroll
    for (int i = 0; i < 4; ++i)
#pragma unroll
        for (int j = 0; j < 2; ++j) acc[i][j] = (f32x4){0.f, 0.f, 0.f, 0.f};
    uint4 av[4], bv[2];
#pragma unroll
    for (int i = 0; i < 4; ++i) av[i] = ((const uint4*)asrc)[i];
    bv[0] = ((const uint4*)bsrc)[0];
    bv[1] = ((const uint4*)bsrc)[1];
    for (int kb = 0; kb < 32; ++kb) {
        __syncthreads();
#pragma unroll
        for (int j = 0; j < 4; ++j)
            *(uint4*)&As[srow][((ca0 + j) ^ ra7) * 8] = av[j];
        *(uint4*)&Bs[brow][((q * 2)     ^ rb7) * 8] = bv[0];
        *(uint4*)&Bs[brow][((q * 2 + 1) ^ rb7) * 8] = bv[1];
        __syncthreads();
        if (kb + 1 < 32) {
#pragma unroll
            for (int i = 0; i < 4; ++i) av[i] = ((const uint4*)(asrc + (kb + 1) * 64))[i];
            bv[0] = ((const uint4*)(bsrc + (kb + 1) * 64))[0];
            bv[1] = ((const uint4*)(bsrc + (kb + 1) * 64))[1];
        }
        bf16x8 ah[4], al[4], bh[2], bl[2];
#pragma unroll
        for (int i = 0; i < 4; ++i) {
            int ra = wm * 64 + i * 16 + fr;
            ah[i] = *(const bf16x8*)&As[ra][((g)     ^ (ra & 7)) * 8];
            al[i] = *(const bf16x8*)&As[ra][((4 + g) ^ (ra & 7)) * 8];
        }
#pragma unroll
        for (int i = 0; i < 2; ++i) {
            int rb = wn * 32 + i * 16 + fr;
            bh[i] = *(const bf16x8*)&Bs[rb][((g)     ^ (rb & 7)) * 8];
            bl[i] = *(const bf16x8*)&Bs[rb][((4 + g) ^ (rb & 7)) * 8];
        }
#pragma unroll
        for (int mi = 0; mi < 4; ++mi)
#pragma unroll
            for (int ni = 0; ni < 2; ++ni) {
                acc[mi][ni] = __builtin_amdgcn_mfma_f32_16x16x32_bf16(ah[mi], bh[ni], acc[mi][ni], 0, 0, 0);
                acc[mi][ni] = __builtin_amdgcn_mfma_f32_16x16x32_bf16(ah[mi], bl[ni], acc[mi][ni], 0, 0, 0);
                acc[mi][ni] = __builtin_amdgcn_mfma_f32_16x16x32_bf16(al[mi], bh[ni], acc[mi][ni], 0, 0, 0);
            }
    }
    const int r0 = g * 4;
#pragma unroll
    for (int mi = 0; mi < 4; ++mi)
#pragma unroll
        for (int ni = 0; ni < 2; ++ni) {
#pragma unroll
            for (int r = 0; r < 4; ++r) {
                int row = bm * 128 + wm * 64 + mi * 16 + r0 + r;
                int col = bn * 64 + wn * 32 + ni * 16 + fr;
                y[(size_t)row * 1024 + col] = acc[mi][ni][r];
            }
        }
}

// -------------------------------------------------- RMS norm + scatter rows
__global__ __launch_bounds__(256) void k_rms(const float* __restrict__ y,
                                             const int* __restrict__ idxs,
                                             const float* __restrict__ w,
                                             float* __restrict__ out) {
    const int r = blockIdx.x;
    const int b = r >> 10, m = r & 1023;
    const float4 v = ((const float4*)(y + (size_t)r * 1024))[threadIdx.x];
    double ss = (double)v.x * v.x + (double)v.y * v.y + (double)v.z * v.z + (double)v.w * v.w;
    int lane = threadIdx.x & 63, wid = threadIdx.x >> 6;
#pragma unroll
    for (int o = 32; o; o >>= 1) ss += __shfl_down(ss, o);
    __shared__ double wr[4];
    if (lane == 0) wr[wid] = ss;
    __syncthreads();
    double tot = wr[0] + wr[1] + wr[2] + wr[3];
    float sc = 1.0f / sqrtf((float)(tot * (1.0 / 1024.0)) + RMSEPS);
    float4 wv = ((const float4*)w)[threadIdx.x];
    int row = idxs[b * KSEL + m];
    float4 o4 = make_float4((v.x * sc) * wv.x, (v.y * sc) * wv.y,
                            (v.z * sc) * wv.z, (v.w * sc) * wv.w);
    ((float4*)(out + ((size_t)b * S_LEN + row) * 1024))[threadIdx.x] = o4;
}

// ----------------------------------------------------------------- launcher
extern "C" void kernel_launch(void* const* d_in, const int* in_sizes, int n_in,
                              void* d_out, int out_size, void* d_ws, size_t ws_size,
                              hipStream_t stream) {
    (void)in_sizes; (void)n_in; (void)out_size; (void)ws_size;
    const float* x     = (const float*)d_in[0];
    const float* cheby = (const float*)d_in[1];
    const float* Wqkv  = (const float*)d_in[2];
    const float* Wo    = (const float*)d_in[3];
    const float* rmsw  = (const float*)d_in[4];
    const float* dll   = (const float*)d_in[5];
    float* out = (float*)d_out;

    float* ws = (float*)d_ws;
    float* scores = ws;                                   // 16384 f
    int*   indices = (int*)(ws + 16384);                  // 2048 i
    float* rcos = ws + 18432;                             // 65536 f
    float* rsin = rcos + 65536;                           // 65536 f
    float* qkv  = rsin + 65536;                           // 8388608 f (32MB)
    ushort* XpAp = (ushort*)(qkv + 8388608);              // 8MB: Xp, then reused as Ap
    ushort* Wqp  = (ushort*)((float*)XpAp + 2097152);     // 16MB
    ushort* Wop  = (ushort*)((float*)Wqp + 4194304);      // 4MB
    float* yb    = (float*)Wop + 1048576;                 // 8MB
    // total ~71.5MB

    k_zero<<<16384, 256, 0, stream>>>((float4*)out, (B_SZ * S_LEN * DMODEL) / 4);
    k_scores<<<B_SZ * (S_LEN - 1), 256, 0, stream>>>(x, cheby, scores);
    k_splitW<<<2048, 256, 0, stream>>>(Wqkv, Wqp, 4096 * 1024);
    k_splitW<<<512, 256, 0, stream>>>(Wo, Wop, 1024 * 1024);
    k_topk<<<B_SZ, 1024, 0, stream>>>(scores, indices);
    k_rope_tab<<<(B_SZ * KSEL * 32 + 255) / 256, 256, 0, stream>>>(indices, rcos, rsin);
    k_splitX<<<B_SZ * KSEL, 256, 0, stream>>>(x, indices, XpAp);
    k_qkv<<<dim3(16, 32), 256, 0, stream>>>(XpAp, Wqp, qkv);
    k_rope_apply<<<B_SZ * KSEL, 256, 0, stream>>>(qkv, rcos, rsin);
    k_attn<<<512, 256, 0, stream>>>(qkv, indices, dll, XpAp);   // writes Ap (aliases Xp, dead)
    k_ogemm<<<dim3(16, 16), 256, 0, stream>>>(XpAp, Wop, yb);
    k_rms<<<B_SZ * KSEL, 256, 0, stream>>>(yb, indices, rmsw, out);
}